// Round 2
// baseline (486.265 us; speedup 1.0000x reference)
//
#include <hip/hip_runtime.h>
#include <stdint.h>

// ---------------------------------------------------------------------------
// MultiHeadLinearAttention (B=4,S=8192,D=512,H=8,dk=64), fp32 in/out.
// Round 5: proj/out_gemm now use the m201-style PHASED schedule (T3+T4+T5):
// per K-tile, 4 phases; each phase = {ds_read this phase's fragments;
// (phase0: issue ALL next-tile global_load_lds); s_barrier; lgkmcnt(0)+
// sched_barrier(0); setprio(1); 16-MFMA cluster; setprio(0); s_barrier}.
// Stage-wait is a single vmcnt(0) in phase 3 — issued 3 phases earlier, so
// the wait is off the latency critical path (issue->wait ~1500+ cyc > 900).
// Round-1 lesson: coarse tile-level dbuf+vmcnt was NEUTRAL (154.5us, MfmaUtil
// 29%) — the lever is the per-phase interleave + setprio role-split (m196/
// m218b), not load-across-barrier alone.
// Also T1: XCD-aware block swizzle (512 blocks per slice, %8==0 -> simple
// bijective form) so the 4 nt-siblings sharing an A panel share one L2.
// XOR swizzle (verified round-2, 0 bank conflicts): logical (row, octet e8)
// stored at row*64 + ((e8^(row&7))*8); global source pre-swizzled so the
// linear wave-order gload_lds write lands at the swizzled slot.
// MFMA 16x16x32_bf16 layouts (verified m89/m91):
//   A: m=lane&15, k=quad*8+j ; B: n=lane&15, k=quad*8+j
//   D: col=lane&15, row=quad*4+r
// ---------------------------------------------------------------------------

#define DMODEL 512
#define NHEAD 8
#define BATCH 4
#define SEQ 8192
#define BSROWS (BATCH * SEQ) // 32768
#define NSPLIT 16
#define CHUNK (SEQ / NSPLIT) // 512

typedef __attribute__((ext_vector_type(8))) short short8;
typedef __attribute__((ext_vector_type(4))) short short4v;
typedef __attribute__((ext_vector_type(4))) float f32x4;
typedef __attribute__((ext_vector_type(4))) unsigned short ushort4v;

__device__ __forceinline__ unsigned short f2bf(float f) {
  union { float f; uint32_t u; } v; v.f = f;
  uint32_t u = v.u;
  u += 0x7fffu + ((u >> 16) & 1u); // RNE
  return (unsigned short)(u >> 16);
}
__device__ __forceinline__ float bf2f(unsigned short h) {
  union { float f; uint32_t u; } v; v.u = ((uint32_t)h) << 16; return v.f;
}
__device__ __forceinline__ f32x4 zero4() {
  f32x4 z; z[0] = 0.f; z[1] = 0.f; z[2] = 0.f; z[3] = 0.f; return z;
}
__device__ __forceinline__ void gload_lds16(const unsigned short* g, unsigned short* l) {
  __builtin_amdgcn_global_load_lds((const __attribute__((address_space(1))) void*)g,
                                   (__attribute__((address_space(3))) void*)l, 16, 0, 0);
}

// ---------------------------------------------------------------------------
struct WPtrs { const float* w[7]; };

__global__ void convert_weights_kernel(WPtrs wp, unsigned short* __restrict__ wbf) {
  int gid = blockIdx.x * 256 + threadIdx.x;  // 458752 total
  int which = gid >> 16;                     // 65536 float4 per matrix
  int rem = gid & 65535;
  float4 v = ((const float4*)wp.w[which])[rem];
  ushort4v o;
  o[0] = f2bf(v.x); o[1] = f2bf(v.y); o[2] = f2bf(v.z); o[3] = f2bf(v.w);
  *(ushort4v*)(wbf + (size_t)which * 262144 + (size_t)rem * 4) = o;
}

__global__ void convert_x_kernel(const float* __restrict__ q, const float* __restrict__ k,
                                 const float* __restrict__ v, unsigned short* __restrict__ xbf) {
  size_t t = (size_t)blockIdx.x * 256 + threadIdx.x; // 6291456 threads, 8 elems each
  int which = (int)(t >> 21);
  size_t rem = t & 2097151;
  const float* src = which == 0 ? q : (which == 1 ? k : v);
  const float4* s4 = (const float4*)src + rem * 2;
  float4 a = s4[0], b = s4[1];
  short8 o;
  o[0] = (short)f2bf(a.x); o[1] = (short)f2bf(a.y);
  o[2] = (short)f2bf(a.z); o[3] = (short)f2bf(a.w);
  o[4] = (short)f2bf(b.x); o[5] = (short)f2bf(b.y);
  o[6] = (short)f2bf(b.z); o[7] = (short)f2bf(b.w);
  *(short8*)(xbf + ((size_t)which << 24) + rem * 8) = o;
}

// ---------------------------------------------------------------------------
// Gated projection: 256x128 tile, 8 waves x (64x64), dual accumulators,
// 4-phase-per-K-tile schedule.
struct ProjArgs {
  const float* b1[3];
  const float* b2[3];
  unsigned short* out[3]; // which0: phiQ [m][512]; which1/2: [bh][d][8192]
};

__global__ __launch_bounds__(512, 2) void proj_kernel(ProjArgs pa,
                                                      const unsigned short* __restrict__ wbf,
                                                      const unsigned short* __restrict__ xbf) {
  const int which = blockIdx.y;
  const unsigned short* __restrict__ x = xbf + ((size_t)which << 24);
  const unsigned short* __restrict__ w1 = wbf + (size_t)which * 524288;
  const unsigned short* __restrict__ w2 = w1 + 262144;
  const float* __restrict__ b1p = pa.b1[which];
  const float* __restrict__ b2p = pa.b2[which];
  unsigned short* __restrict__ outp = pa.out[which];
  const bool PHI = (which < 2);

  // T1: XCD-aware bijective swizzle; 512 blocks/slice, 512%8==0.
  const int wg = (blockIdx.x & 7) * 64 + (blockIdx.x >> 3);
  const int mt = wg >> 2, nt = wg & 3;
  const int m0 = mt * 256, n0 = nt * 128;
  const int tid = threadIdx.x;
  const int wave = tid >> 6, lane = tid & 63;
  const int lrow = lane & 15, quad = lane >> 4;
  const int m_off = (wave >> 1) * 64, n_off = (wave & 1) * 64;

  // Per buffer (shorts): A[0..16384) 256x64, B1[16384..24576) 128x64,
  // B2[24576..32768) 128x64.  Two buffers -> 65536 shorts = 128 KB.
  __shared__ unsigned short lds[2 * 32768];

  const int srow_l = lane >> 3;            // 0..7 within 8-row issue
  const int kq_l = (lane & 7) ^ srow_l;    // swizzled source octet
  const int swz = lrow & 7;

  f32x4 acc1[4][4], acc2[4][4];
#pragma unroll
  for (int i = 0; i < 4; i++)
#pragma unroll
    for (int j = 0; j < 4; j++) { acc1[i][j] = zero4(); acc2[i][j] = zero4(); }

  auto stage = [&](unsigned short* dst, int k0) {
#pragma unroll
    for (int i = 0; i < 4; i++) {
      int ig = wave * 4 + i;               // 32 issues cover A 256x64
      gload_lds16(x + (size_t)(m0 + ig * 8 + srow_l) * 512 + k0 + kq_l * 8,
                  dst + ig * 512);
    }
#pragma unroll
    for (int j = 0; j < 2; j++) {
      int igb = wave * 2 + j;              // 16 issues cover each B 128x64
      size_t roff = (size_t)(n0 + igb * 8 + srow_l) * 512 + k0 + kq_l * 8;
      gload_lds16(w1 + roff, dst + 16384 + igb * 512);
      gload_lds16(w2 + roff, dst + 24576 + igb * 512);
    }
  };

  // ---- prologue: stage tile 0 ----
  stage(lds, 0);
  asm volatile("s_waitcnt vmcnt(0)" ::: "memory");
  __builtin_amdgcn_s_barrier();

  for (int t = 0; t < 8; ++t) {
    unsigned short* cur = lds + (t & 1) * 32768;
    unsigned short* nxt = lds + ((t + 1) & 1) * 32768;
    short8 af[4], b1f[4], b2f[4];

    // ================= phase 0: af(kk0)+b1f(kk0); stage t+1; acc1 =========
    {
      const int e8 = quad; // kk=0
#pragma unroll
      for (int mi = 0; mi < 4; mi++)
        af[mi] = *(const short8*)(cur + (m_off + mi * 16 + lrow) * 64 + ((e8 ^ swz) << 3));
#pragma unroll
      for (int ni = 0; ni < 4; ni++)
        b1f[ni] = *(const short8*)(cur + 16384 + (n_off + ni * 16 + lrow) * 64 + ((e8 ^ swz) << 3));
    }
    if (t < 7) stage(nxt, (t + 1) * 64);
    __builtin_amdgcn_s_barrier();
    asm volatile("s_waitcnt lgkmcnt(0)" ::: "memory");
    __builtin_amdgcn_sched_barrier(0);
    __builtin_amdgcn_s_setprio(1);
#pragma unroll
    for (int ni = 0; ni < 4; ni++)
#pragma unroll
      for (int mi = 0; mi < 4; mi++)
        acc1[mi][ni] = __builtin_amdgcn_mfma_f32_16x16x32_bf16(af[mi], b1f[ni], acc1[mi][ni], 0, 0, 0);
    __builtin_amdgcn_s_setprio(0);
    __builtin_amdgcn_s_barrier();

    // ================= phase 1: b2f(kk0); acc2 (reuse af) =================
    {
      const int e8 = quad;
#pragma unroll
      for (int ni = 0; ni < 4; ni++)
        b2f[ni] = *(const short8*)(cur + 24576 + (n_off + ni * 16 + lrow) * 64 + ((e8 ^ swz) << 3));
    }
    __builtin_amdgcn_s_barrier();
    asm volatile("s_waitcnt lgkmcnt(0)" ::: "memory");
    __builtin_amdgcn_sched_barrier(0);
    __builtin_amdgcn_s_setprio(1);
#pragma unroll
    for (int ni = 0; ni < 4; ni++)
#pragma unroll
      for (int mi = 0; mi < 4; mi++)
        acc2[mi][ni] = __builtin_amdgcn_mfma_f32_16x16x32_bf16(af[mi], b2f[ni], acc2[mi][ni], 0, 0, 0);
    __builtin_amdgcn_s_setprio(0);
    __builtin_amdgcn_s_barrier();

    // ================= phase 2: af(kk1)+b1f(kk1); acc1 ====================
    {
      const int e8 = 4 + quad; // kk=32
#pragma unroll
      for (int mi = 0; mi < 4; mi++)
        af[mi] = *(const short8*)(cur + (m_off + mi * 16 + lrow) * 64 + ((e8 ^ swz) << 3));
#pragma unroll
      for (int ni = 0; ni < 4; ni++)
        b1f[ni] = *(const short8*)(cur + 16384 + (n_off + ni * 16 + lrow) * 64 + ((e8 ^ swz) << 3));
    }
    __builtin_amdgcn_s_barrier();
    asm volatile("s_waitcnt lgkmcnt(0)" ::: "memory");
    __builtin_amdgcn_sched_barrier(0);
    __builtin_amdgcn_s_setprio(1);
#pragma unroll
    for (int ni = 0; ni < 4; ni++)
#pragma unroll
      for (int mi = 0; mi < 4; mi++)
        acc1[mi][ni] = __builtin_amdgcn_mfma_f32_16x16x32_bf16(af[mi], b1f[ni], acc1[mi][ni], 0, 0, 0);
    __builtin_amdgcn_s_setprio(0);
    __builtin_amdgcn_s_barrier();

    // ================= phase 3: b2f(kk1); vmcnt(0); acc2 ==================
    {
      const int e8 = 4 + quad;
#pragma unroll
      for (int ni = 0; ni < 4; ni++)
        b2f[ni] = *(const short8*)(cur + 24576 + (n_off + ni * 16 + lrow) * 64 + ((e8 ^ swz) << 3));
    }
    // wait for t+1 staging (issued 3 phases ago -> latency already hidden)
    asm volatile("s_waitcnt vmcnt(0)" ::: "memory");
    __builtin_amdgcn_s_barrier();
    asm volatile("s_waitcnt lgkmcnt(0)" ::: "memory");
    __builtin_amdgcn_sched_barrier(0);
    __builtin_amdgcn_s_setprio(1);
#pragma unroll
    for (int ni = 0; ni < 4; ni++)
#pragma unroll
      for (int mi = 0; mi < 4; mi++)
        acc2[mi][ni] = __builtin_amdgcn_mfma_f32_16x16x32_bf16(af[mi], b2f[ni], acc2[mi][ni], 0, 0, 0);
    __builtin_amdgcn_s_setprio(0);
    __builtin_amdgcn_s_barrier();
  }

  if (which == 0) {
#pragma unroll
    for (int ni = 0; ni < 4; ni++) {
      int n = n0 + n_off + ni * 16 + lrow;
      float bb1 = b1p[n], bb2 = b2p[n];
#pragma unroll
      for (int mi = 0; mi < 4; mi++)
#pragma unroll
        for (int r = 0; r < 4; r++) {
          int m = m0 + m_off + mi * 16 + quad * 4 + r;
          float v1 = acc1[mi][ni][r] + bb1;
          float v2 = acc2[mi][ni][r] + bb2;
          float y = v1 * (1.f / (1.f + __expf(-v1))) * v2; // silu(v1)*v2
          y = (y > 0.f) ? (y + 1.f) : __expf(y);           // elu(y)+1
          outp[(size_t)m * 512 + n] = f2bf(y);
        }
    }
  } else {
    // transposed store: [bh][d][s], 8B (4 consecutive s) per lane per (mi,ni)
    const int bI = m0 >> 13;
    const int sb = (m0 & 8191) + m_off + quad * 4;
#pragma unroll
    for (int ni = 0; ni < 4; ni++) {
      int n = n0 + n_off + ni * 16 + lrow;
      float bb1 = b1p[n], bb2 = b2p[n];
      int h = n >> 6, d = n & 63;
      unsigned short* dst0 = outp + (((size_t)bI * 8 + h) * 64 + d) * 8192 + sb;
#pragma unroll
      for (int mi = 0; mi < 4; mi++) {
        short4v o;
#pragma unroll
        for (int r = 0; r < 4; r++) {
          float v1 = acc1[mi][ni][r] + bb1;
          float v2 = acc2[mi][ni][r] + bb2;
          float y = v1 * (1.f / (1.f + __expf(-v1))) * v2;
          if (PHI) y = (y > 0.f) ? (y + 1.f) : __expf(y);
          o[r] = (short)f2bf(y);
        }
        *(short4v*)(dst0 + mi * 16) = o;
      }
    }
  }
}

// ---------------------------------------------------------------------------
// KV^T partials from transposed inputs: D[e][d] = sum_s vT[e][s]*kT[d][s].
__global__ __launch_bounds__(256) void kv_kernel(const unsigned short* __restrict__ kT,
                                                 const unsigned short* __restrict__ vT,
                                                 float* __restrict__ kvt_part,
                                                 float* __restrict__ ksum_part) {
  const int chunk = blockIdx.x & (NSPLIT - 1);
  const int bh = blockIdx.x >> 4;
  const int tid = threadIdx.x;
  const int wave = tid >> 6, lane = tid & 63;
  const int lrow = lane & 15, quad = lane >> 4;

  __shared__ float ls_acc[4096];
  __shared__ float ls_ksum[64];
  if (tid < 64) ls_ksum[tid] = 0.f;
#pragma unroll
  for (int i = 0; i < 16; i++) ls_acc[tid + 256 * i] = 0.f;

  const unsigned short* vrow = vT + (size_t)bh * 64 * 8192;
  const unsigned short* krow = kT + (size_t)bh * 64 * 8192;
  const int s_w = chunk * CHUNK + wave * 128;

  short8 ones;
#pragma unroll
  for (int j = 0; j < 8; j++) ones[j] = (short)0x3F80; // bf16 1.0

  f32x4 acc[4][4], aks[4];
#pragma unroll
  for (int i = 0; i < 4; i++) {
    aks[i] = zero4();
#pragma unroll
    for (int j = 0; j < 4; j++) acc[i][j] = zero4();
  }

  for (int it = 0; it < 4; it++) {
    const int s0 = s_w + it * 32 + quad * 8;
    short8 af[4], bfr[4];
#pragma unroll
    for (int mi = 0; mi < 4; mi++)
      af[mi] = *(const short8*)(vrow + (size_t)(mi * 16 + lrow) * 8192 + s0);
#pragma unroll
    for (int ni = 0; ni < 4; ni++)
      bfr[ni] = *(const short8*)(krow + (size_t)(ni * 16 + lrow) * 8192 + s0);
#pragma unroll
    for (int ni = 0; ni < 4; ni++) {
      aks[ni] = __builtin_amdgcn_mfma_f32_16x16x32_bf16(ones, bfr[ni], aks[ni], 0, 0, 0);
#pragma unroll
      for (int mi = 0; mi < 4; mi++)
        acc[mi][ni] = __builtin_amdgcn_mfma_f32_16x16x32_bf16(af[mi], bfr[ni], acc[mi][ni], 0, 0, 0);
    }
  }

  __syncthreads();
#pragma unroll
  for (int mi = 0; mi < 4; mi++)
#pragma unroll
    for (int ni = 0; ni < 4; ni++)
#pragma unroll
      for (int r = 0; r < 4; r++)
        atomicAdd(&ls_acc[(mi * 16 + quad * 4 + r) * 64 + ni * 16 + lrow], acc[mi][ni][r]);
  if (quad == 0) {
#pragma unroll
    for (int ni = 0; ni < 4; ni++) atomicAdd(&ls_ksum[ni * 16 + lrow], aks[ni][0]);
  }
  __syncthreads();

  float* op = kvt_part + ((size_t)chunk * 32 + bh) * 4096;
#pragma unroll
  for (int i = 0; i < 16; i++) op[tid + 256 * i] = ls_acc[tid + 256 * i];
  if (tid < 64) ksum_part[((size_t)chunk * 32 + bh) * 64 + tid] = ls_ksum[tid];
}

// ---------------------------------------------------------------------------
__global__ void kv_reduce_kernel(const float* __restrict__ kvt_part,
                                 const float* __restrict__ ksum_part,
                                 unsigned short* __restrict__ kvT,
                                 unsigned short* __restrict__ ksum_bf) {
  const int bh = blockIdx.x >> 2, seg = blockIdx.x & 3;
  const int idx = seg * 1024 + threadIdx.x * 4;
  float4 s = make_float4(0.f, 0.f, 0.f, 0.f);
#pragma unroll
  for (int c = 0; c < NSPLIT; c++) {
    float4 v = *(const float4*)&kvt_part[((size_t)c * 32 + bh) * 4096 + idx];
    s.x += v.x; s.y += v.y; s.z += v.z; s.w += v.w;
  }
  ushort4v o;
  o[0] = f2bf(s.x); o[1] = f2bf(s.y); o[2] = f2bf(s.z); o[3] = f2bf(s.w);
  *(ushort4v*)(kvT + (size_t)bh * 4096 + idx) = o;
  if (seg == 0 && threadIdx.x < 64) {
    float t = 0.f;
#pragma unroll
    for (int c = 0; c < NSPLIT; c++) t += ksum_part[((size_t)c * 32 + bh) * 64 + threadIdx.x];
    ksum_bf[bh * 64 + threadIdx.x] = f2bf(t);
  }
}

// ---------------------------------------------------------------------------
// numerator = phiQ @ KV, qk_sum = phiQ @ ksum (broadcast-column B => extra
// MFMA whose D rows line up lane-for-lane with the numerator rows).
__global__ __launch_bounds__(256) void attn_kernel(const unsigned short* __restrict__ phiQ,
                                                   const unsigned short* __restrict__ kvT,
                                                   const unsigned short* __restrict__ ksum_bf,
                                                   unsigned short* __restrict__ xattn) {
  const int bh = blockIdx.x & 31;
  const int st = blockIdx.x >> 5;
  const int b = bh >> 3, h = bh & 7;
  const int tid = threadIdx.x;
  const int wave = tid >> 6, lane = tid & 63;
  const int lrow = lane & 15, quad = lane >> 4;
  const size_t rowbase = (size_t)b * SEQ + st * 128 + wave * 32;

  f32x4 acc[2][4], aqs[2];
#pragma unroll
  for (int i = 0; i < 2; i++) {
    aqs[i] = zero4();
#pragma unroll
    for (int j = 0; j < 4; j++) acc[i][j] = zero4();
  }

#pragma unroll
  for (int kk = 0; kk < 64; kk += 32) {
    short8 ks = *(const short8*)(ksum_bf + bh * 64 + kk + quad * 8);
    short8 af[2];
#pragma unroll
    for (int mi = 0; mi < 2; mi++)
      af[mi] = *(const short8*)(phiQ + (rowbase + mi * 16 + lrow) * 512 + h * 64 + kk + quad * 8);
#pragma unroll
    for (int mi = 0; mi < 2; mi++)
      aqs[mi] = __builtin_amdgcn_mfma_f32_16x16x32_bf16(af[mi], ks, aqs[mi], 0, 0, 0);
#pragma unroll
    for (int ni = 0; ni < 4; ni++) {
      short8 bfr = *(const short8*)(kvT + (size_t)bh * 4096 + (ni * 16 + lrow) * 64 + kk + quad * 8);
#pragma unroll
      for (int mi = 0; mi < 2; mi++)
        acc[mi][ni] = __builtin_amdgcn_mfma_f32_16x16x32_bf16(af[mi], bfr, acc[mi][ni], 0, 0, 0);
    }
  }
#pragma unroll
  for (int mi = 0; mi < 2; mi++) {
#pragma unroll
    for (int r = 0; r < 4; r++) {
      float inv = 1.f / (aqs[mi][r] + 1e-6f);
      size_t m = rowbase + mi * 16 + quad * 4 + r;
#pragma unroll
      for (int ni = 0; ni < 4; ni++)
        xattn[m * 512 + h * 64 + ni * 16 + lrow] = f2bf(acc[mi][ni][r] * inv);
    }
  }
}

// ---------------------------------------------------------------------------
// out_gemm: same 4-phase schedule, single B operand (phases = kk x ni-half).
__global__ __launch_bounds__(512, 2) void out_gemm_kernel(const unsigned short* __restrict__ xattn,
                                                          const unsigned short* __restrict__ wo,
                                                          const float* __restrict__ ob,
                                                          float* __restrict__ out) {
  const int wg = (blockIdx.x & 7) * 64 + (blockIdx.x >> 3); // T1 swizzle
  const int mt = wg >> 2, nt = wg & 3;
  const int m0 = mt * 256, n0 = nt * 128;
  const int tid = threadIdx.x;
  const int wave = tid >> 6, lane = tid & 63;
  const int lrow = lane & 15, quad = lane >> 4;
  const int m_off = (wave >> 1) * 64, n_off = (wave & 1) * 64;

  // Per buffer (shorts): A[0..16384) 256x64, B[16384..24576) 128x64.
  __shared__ unsigned short lds[2 * 24576]; // 96 KB

  const int srow_l = lane >> 3;
  const int kq_l = (lane & 7) ^ srow_l;
  const int swz = lrow & 7;

  f32x4 acc[4][4];
#pragma unroll
  for (int i = 0; i < 4; i++)
#pragma unroll
    for (int j = 0; j < 4; j++) acc[i][j] = zero4();

  auto stage = [&](unsigned short* dst, int k0) {
#pragma unroll
    for (int i = 0; i < 4; i++) {
      int ig = wave * 4 + i;
      gload_lds16(xattn + (size_t)(m0 + ig * 8 + srow_l) * 512 + k0 + kq_l * 8,
                  dst + ig * 512);
    }
#pragma unroll
    for (int j = 0; j < 2; j++) {
      int igb = wave * 2 + j;
      gload_lds16(wo + (size_t)(n0 + igb * 8 + srow_l) * 512 + k0 + kq_l * 8,
                  dst + 16384 + igb * 512);
    }
  };

  stage(lds, 0);
  asm volatile("s_waitcnt vmcnt(0)" ::: "memory");
  __builtin_amdgcn_s_barrier();

  for (int t = 0; t < 8; ++t) {
    unsigned short* cur = lds + (t & 1) * 24576;
    unsigned short* nxt = lds + ((t + 1) & 1) * 24576;
    short8 af[4], bfr[4];

#pragma unroll
    for (int half = 0; half < 2; half++) {   // kk = half*32
      const int e8 = half * 4 + quad;
      // -------- phase A: af(kk)+bf(kk, ni 0..1); (half0: stage t+1) -------
#pragma unroll
      for (int mi = 0; mi < 4; mi++)
        af[mi] = *(const short8*)(cur + (m_off + mi * 16 + lrow) * 64 + ((e8 ^ swz) << 3));
#pragma unroll
      for (int ni = 0; ni < 2; ni++)
        bfr[ni] = *(const short8*)(cur + 16384 + (n_off + ni * 16 + lrow) * 64 + ((e8 ^ swz) << 3));
      if (half == 0 && t < 7) stage(nxt, (t + 1) * 64);
      __builtin_amdgcn_s_barrier();
      asm volatile("s_waitcnt lgkmcnt(0)" ::: "memory");
      __builtin_amdgcn_sched_barrier(0);
      __builtin_amdgcn_s_setprio(1);
#pragma unroll
      for (int ni = 0; ni < 2; ni++)
#pragma unroll
        for (int mi = 0; mi < 4; mi++)
          acc[mi][ni] = __builtin_amdgcn_mfma_f32_16x16x32_bf16(af[mi], bfr[ni], acc[mi][ni], 0, 0, 0);
      __builtin_amdgcn_s_setprio(0);
      __builtin_amdgcn_s_barrier();
      // -------- phase B: bf(kk, ni 2..3); (half1: vmcnt) ------------------
#pragma unroll
      for (int ni = 2; ni < 4; ni++)
        bfr[ni] = *(const short8*)(cur + 16384 + (n_off + ni * 16 + lrow) * 64 + ((e8 ^ swz) << 3));
      if (half == 1) asm volatile("s_waitcnt vmcnt(0)" ::: "memory");
      __builtin_amdgcn_s_barrier();
      asm volatile("s_waitcnt lgkmcnt(0)" ::: "memory");
      __builtin_amdgcn_sched_barrier(0);
      __builtin_amdgcn_s_setprio(1);
#pragma unroll
      for (int ni = 2; ni < 4; ni++)
#pragma unroll
        for (int mi = 0; mi < 4; mi++)
          acc[mi][ni] = __builtin_amdgcn_mfma_f32_16x16x32_bf16(af[mi], bfr[ni], acc[mi][ni], 0, 0, 0);
      __builtin_amdgcn_s_setprio(0);
      __builtin_amdgcn_s_barrier();
    }
  }

#pragma unroll
  for (int ni = 0; ni < 4; ni++) {
    int n = n0 + n_off + ni * 16 + lrow;
    float bb = ob[n];
#pragma unroll
    for (int mi = 0; mi < 4; mi++)
#pragma unroll
      for (int r = 0; r < 4; r++) {
        int m = m0 + m_off + mi * 16 + quad * 4 + r;
        out[(size_t)m * 512 + n] = acc[mi][ni][r] + bb;
      }
  }
}

// ---------------------------------------------------------------------------
extern "C" void kernel_launch(void* const* d_in, const int* in_sizes, int n_in,
                              void* d_out, int out_size, void* d_ws, size_t ws_size,
                              hipStream_t stream) {
  char* ws = (char*)d_ws;
  size_t off = 0;
  auto alloc = [&](size_t bytes) -> void* {
    void* p = ws + off;
    off += (bytes + 255) & ~(size_t)255;
    return p;
  };
  unsigned short* wbf = (unsigned short*)alloc((size_t)7 * 262144 * 2);     // 3.67 MB
  unsigned short* phiQ = (unsigned short*)alloc((size_t)BSROWS * 512 * 2);  // 33.5 MB
  unsigned short* kT = (unsigned short*)alloc((size_t)BSROWS * 512 * 2);    // 33.5 MB  [bh][d][s]
  unsigned short* vT = (unsigned short*)alloc((size_t)BSROWS * 512 * 2);    // 33.5 MB  [bh][e][s]
  unsigned short* xbf = (unsigned short*)alloc((size_t)3 * BSROWS * 512 * 2); // 100.7 MB
  if (off > ws_size) return; // insufficient workspace; fail visibly

  // xbf region reused after proj_kernel: x_attn + kv partials
  char* xr = (char*)xbf;
  unsigned short* xattn = (unsigned short*)xr;              // 67,108,864 B
  float* kvt_part = (float*)(xr + 67108864);                //  8,388,608 B
  float* ksum_part = (float*)(xr + 75497472);               //    131,072 B
  unsigned short* kvT = (unsigned short*)(xr + 75628544);   //    262,144 B
  unsigned short* ksum_bf = (unsigned short*)(xr + 75890688);

  WPtrs wp;
  for (int i = 0; i < 7; i++) wp.w[i] = (const float*)d_in[3 + i];
  convert_weights_kernel<<<1792, 256, 0, stream>>>(wp, wbf);
  convert_x_kernel<<<24576, 256, 0, stream>>>((const float*)d_in[0], (const float*)d_in[1],
                                              (const float*)d_in[2], xbf);

  ProjArgs pa;
  pa.b1[0] = (const float*)d_in[10]; pa.b2[0] = (const float*)d_in[11];
  pa.b1[1] = (const float*)d_in[12]; pa.b2[1] = (const float*)d_in[13];
  pa.b1[2] = (const float*)d_in[14]; pa.b2[2] = (const float*)d_in[15];
  pa.out[0] = phiQ; pa.out[1] = kT; pa.out[2] = vT;
  proj_kernel<<<dim3(512, 3), 512, 0, stream>>>(pa, wbf, xbf);

  kv_kernel<<<512, 256, 0, stream>>>(kT, vT, kvt_part, ksum_part);
  kv_reduce_kernel<<<128, 256, 0, stream>>>(kvt_part, ksum_part, kvT, ksum_bf);
  attn_kernel<<<2048, 256, 0, stream>>>(phiQ, kvT, ksum_bf, xattn);
  out_gemm_kernel<<<512, 512, 0, stream>>>(xattn, wbf + (size_t)6 * 262144,
                                           (const float*)d_in[16], (float*)d_out);
}

// Round 3
// 477.123 us; speedup vs baseline: 1.0192x; 1.0192x over previous
//
#include <hip/hip_runtime.h>
#include <stdint.h>

// ---------------------------------------------------------------------------
// MultiHeadLinearAttention (B=4,S=8192,D=512,H=8,dk=64), fp32 in/out.
// Round 6: TLP-first redesign of proj/out_gemm.
//   Post-mortem model (fits r0/r1/r2 within ~5%): per-CU K-tile time was the
//   SERIAL SUM of MFMA (2484cy) + LDS-read (~2470cy) + staging (~1800cy),
//   because 8 waves / 1 block / 2 waves-per-SIMD in lockstep barriers leave
//   zero independent waves to overlap pipes. Fix: shrink per-wave tile to
//   Wm=64,Wn=32 dual-mat -> acc 64 AGPR + ~60 arch VGPR <= 128 total ->
//   4 waves/SIMD. 16-wave (1024-thread) blocks on a 256x128 tile (4m x 4n).
//   Coarse double-buffer + counted vmcnt(4) (neutral in r1, keeps staging off
//   the critical path); NO setprio / sched_barrier (r2: -30%, pinning +
//   8 barriers/K-tile serialized everything).
//   T1 XCD swizzle KEPT (r2: FETCH 203->74 MB, -64%).
// XOR swizzle (verified: 0 bank conflicts): logical (row, octet e8) stored at
// row*64 + ((e8^(row&7))*8); global source pre-swizzled so the linear
// wave-order global_load_lds write lands at the swizzled slot.
// MFMA 16x16x32_bf16 layouts (verified m89/m91):
//   A: m=lane&15, k=quad*8+j ; B: n=lane&15, k=quad*8+j
//   D: col=lane&15, row=quad*4+r
// ---------------------------------------------------------------------------

#define DMODEL 512
#define NHEAD 8
#define BATCH 4
#define SEQ 8192
#define BSROWS (BATCH * SEQ) // 32768
#define NSPLIT 16
#define CHUNK (SEQ / NSPLIT) // 512

typedef __attribute__((ext_vector_type(8))) short short8;
typedef __attribute__((ext_vector_type(4))) short short4v;
typedef __attribute__((ext_vector_type(4))) float f32x4;
typedef __attribute__((ext_vector_type(4))) unsigned short ushort4v;

__device__ __forceinline__ unsigned short f2bf(float f) {
  union { float f; uint32_t u; } v; v.f = f;
  uint32_t u = v.u;
  u += 0x7fffu + ((u >> 16) & 1u); // RNE
  return (unsigned short)(u >> 16);
}
__device__ __forceinline__ float bf2f(unsigned short h) {
  union { float f; uint32_t u; } v; v.u = ((uint32_t)h) << 16; return v.f;
}
__device__ __forceinline__ f32x4 zero4() {
  f32x4 z; z[0] = 0.f; z[1] = 0.f; z[2] = 0.f; z[3] = 0.f; return z;
}
__device__ __forceinline__ void gload_lds16(const unsigned short* g, unsigned short* l) {
  __builtin_amdgcn_global_load_lds((const __attribute__((address_space(1))) void*)g,
                                   (__attribute__((address_space(3))) void*)l, 16, 0, 0);
}

// ---------------------------------------------------------------------------
struct WPtrs { const float* w[7]; };

__global__ void convert_weights_kernel(WPtrs wp, unsigned short* __restrict__ wbf) {
  int gid = blockIdx.x * 256 + threadIdx.x;  // 458752 total
  int which = gid >> 16;                     // 65536 float4 per matrix
  int rem = gid & 65535;
  float4 v = ((const float4*)wp.w[which])[rem];
  ushort4v o;
  o[0] = f2bf(v.x); o[1] = f2bf(v.y); o[2] = f2bf(v.z); o[3] = f2bf(v.w);
  *(ushort4v*)(wbf + (size_t)which * 262144 + (size_t)rem * 4) = o;
}

__global__ void convert_x_kernel(const float* __restrict__ q, const float* __restrict__ k,
                                 const float* __restrict__ v, unsigned short* __restrict__ xbf) {
  size_t t = (size_t)blockIdx.x * 256 + threadIdx.x; // 6291456 threads, 8 elems each
  int which = (int)(t >> 21);
  size_t rem = t & 2097151;
  const float* src = which == 0 ? q : (which == 1 ? k : v);
  const float4* s4 = (const float4*)src + rem * 2;
  float4 a = s4[0], b = s4[1];
  short8 o;
  o[0] = (short)f2bf(a.x); o[1] = (short)f2bf(a.y);
  o[2] = (short)f2bf(a.z); o[3] = (short)f2bf(a.w);
  o[4] = (short)f2bf(b.x); o[5] = (short)f2bf(b.y);
  o[6] = (short)f2bf(b.z); o[7] = (short)f2bf(b.w);
  *(short8*)(xbf + ((size_t)which << 24) + rem * 8) = o;
}

// ---------------------------------------------------------------------------
// Gated projection: 256x128 tile, 16 waves x (Wm=64 x Wn=32, dual-mat).
// acc = 4mi x 2ni x 2mats x f32x4 = 64 AGPR; target <=128 total regs
// -> 4 waves/SIMD.
struct ProjArgs {
  const float* b1[3];
  const float* b2[3];
  unsigned short* out[3]; // which0: phiQ [m][512]; which1/2: [bh][d][8192]
};

__global__ __launch_bounds__(1024, 4) void proj_kernel(ProjArgs pa,
                                                       const unsigned short* __restrict__ wbf,
                                                       const unsigned short* __restrict__ xbf) {
  const int which = blockIdx.y;
  const unsigned short* __restrict__ x = xbf + ((size_t)which << 24);
  const unsigned short* __restrict__ w1 = wbf + (size_t)which * 524288;
  const unsigned short* __restrict__ w2 = w1 + 262144;
  const float* __restrict__ b1p = pa.b1[which];
  const float* __restrict__ b2p = pa.b2[which];
  unsigned short* __restrict__ outp = pa.out[which];
  const bool PHI = (which < 2);

  // T1: XCD-aware bijective swizzle; 512 blocks/slice, 512%8==0.
  const int wg = (blockIdx.x & 7) * 64 + (blockIdx.x >> 3);
  const int mt = wg >> 2, nt = wg & 3;
  const int m0 = mt * 256, n0 = nt * 128;
  const int tid = threadIdx.x;
  const int wave = tid >> 6, lane = tid & 63;   // wave 0..15
  const int lrow = lane & 15, quad = lane >> 4;
  const int m_off = (wave >> 2) * 64;           // 4 m-positions
  const int n_off = (wave & 3) * 32;            // 4 n-positions

  // Per buffer (shorts): sA[0..16384) 256x64, sB1[16384..24576) 128x64,
  // sB2[24576..32768) 128x64.  Double-buffered -> 65536 shorts = 128 KB.
  __shared__ unsigned short lds[2 * 32768];

  const int srow_l = lane >> 3;            // 0..7 within 8-row issue
  const int kq_l = (lane & 7) ^ srow_l;    // swizzled source octet
  const int swz = lrow & 7;

  f32x4 acc1[4][2], acc2[4][2];
#pragma unroll
  for (int i = 0; i < 4; i++)
#pragma unroll
    for (int j = 0; j < 2; j++) { acc1[i][j] = zero4(); acc2[i][j] = zero4(); }

  // 4 stage issues per wave: 2 for A (32 issues cover 256x64), 1 each B1/B2
  auto stage = [&](unsigned short* dst, int k0) {
#pragma unroll
    for (int i = 0; i < 2; i++) {
      int ig = wave * 2 + i;
      gload_lds16(x + (size_t)(m0 + ig * 8 + srow_l) * 512 + k0 + kq_l * 8,
                  dst + ig * 512);
    }
    size_t roff = (size_t)(n0 + wave * 8 + srow_l) * 512 + k0 + kq_l * 8;
    gload_lds16(w1 + roff, dst + 16384 + wave * 512);
    gload_lds16(w2 + roff, dst + 24576 + wave * 512);
  };

  // prologue: stage tile 0 into buffer 0
  stage(lds, 0);

  for (int t = 0; t < 8; ++t) {
    unsigned short* cur = lds + (t & 1) * 32768;
    if (t < 7) {
      stage(lds + ((t + 1) & 1) * 32768, (t + 1) * 64);
      // 4 newest (tile t+1) stay in flight; tile t's 4 are complete
      asm volatile("s_waitcnt vmcnt(4)" ::: "memory");
    } else {
      asm volatile("s_waitcnt vmcnt(0)" ::: "memory");
    }
    __builtin_amdgcn_s_barrier();   // all waves' tile-t loads landed

#pragma unroll
    for (int kk = 0; kk < 64; kk += 32) {
      const int e8 = (kk >> 3) + quad;
      short8 af[4], b1f[2], b2f[2];
#pragma unroll
      for (int mi = 0; mi < 4; mi++)
        af[mi] = *(const short8*)(cur + (m_off + mi * 16 + lrow) * 64 + ((e8 ^ swz) << 3));
#pragma unroll
      for (int ni = 0; ni < 2; ni++) {
        int rr = n_off + ni * 16 + lrow;
        b1f[ni] = *(const short8*)(cur + 16384 + rr * 64 + ((e8 ^ swz) << 3));
        b2f[ni] = *(const short8*)(cur + 24576 + rr * 64 + ((e8 ^ swz) << 3));
      }
#pragma unroll
      for (int ni = 0; ni < 2; ni++)
#pragma unroll
        for (int mi = 0; mi < 4; mi++) {
          acc1[mi][ni] = __builtin_amdgcn_mfma_f32_16x16x32_bf16(af[mi], b1f[ni], acc1[mi][ni], 0, 0, 0);
          acc2[mi][ni] = __builtin_amdgcn_mfma_f32_16x16x32_bf16(af[mi], b2f[ni], acc2[mi][ni], 0, 0, 0);
        }
    }
    __builtin_amdgcn_s_barrier();   // all reads of cur done before overwrite
  }

  if (which == 0) {
#pragma unroll
    for (int ni = 0; ni < 2; ni++) {
      int n = n0 + n_off + ni * 16 + lrow;
      float bb1 = b1p[n], bb2 = b2p[n];
#pragma unroll
      for (int mi = 0; mi < 4; mi++)
#pragma unroll
        for (int r = 0; r < 4; r++) {
          int m = m0 + m_off + mi * 16 + quad * 4 + r;
          float v1 = acc1[mi][ni][r] + bb1;
          float v2 = acc2[mi][ni][r] + bb2;
          float y = v1 * (1.f / (1.f + __expf(-v1))) * v2; // silu(v1)*v2
          y = (y > 0.f) ? (y + 1.f) : __expf(y);           // elu(y)+1
          outp[(size_t)m * 512 + n] = f2bf(y);
        }
    }
  } else {
    // transposed store: [bh][d][s], 8B (4 consecutive s) per lane per (mi,ni)
    const int bI = m0 >> 13;
    const int sb = (m0 & 8191) + m_off + quad * 4;
#pragma unroll
    for (int ni = 0; ni < 2; ni++) {
      int n = n0 + n_off + ni * 16 + lrow;
      float bb1 = b1p[n], bb2 = b2p[n];
      int h = n >> 6, d = n & 63;
      unsigned short* dst0 = outp + (((size_t)bI * 8 + h) * 64 + d) * 8192 + sb;
#pragma unroll
      for (int mi = 0; mi < 4; mi++) {
        short4v o;
#pragma unroll
        for (int r = 0; r < 4; r++) {
          float v1 = acc1[mi][ni][r] + bb1;
          float v2 = acc2[mi][ni][r] + bb2;
          float y = v1 * (1.f / (1.f + __expf(-v1))) * v2;
          if (PHI) y = (y > 0.f) ? (y + 1.f) : __expf(y);
          o[r] = (short)f2bf(y);
        }
        *(short4v*)(dst0 + mi * 16) = o;
      }
    }
  }
}

// ---------------------------------------------------------------------------
// KV^T partials from transposed inputs: D[e][d] = sum_s vT[e][s]*kT[d][s].
__global__ __launch_bounds__(256) void kv_kernel(const unsigned short* __restrict__ kT,
                                                 const unsigned short* __restrict__ vT,
                                                 float* __restrict__ kvt_part,
                                                 float* __restrict__ ksum_part) {
  const int chunk = blockIdx.x & (NSPLIT - 1);
  const int bh = blockIdx.x >> 4;
  const int tid = threadIdx.x;
  const int wave = tid >> 6, lane = tid & 63;
  const int lrow = lane & 15, quad = lane >> 4;

  __shared__ float ls_acc[4096];
  __shared__ float ls_ksum[64];
  if (tid < 64) ls_ksum[tid] = 0.f;
#pragma unroll
  for (int i = 0; i < 16; i++) ls_acc[tid + 256 * i] = 0.f;

  const unsigned short* vrow = vT + (size_t)bh * 64 * 8192;
  const unsigned short* krow = kT + (size_t)bh * 64 * 8192;
  const int s_w = chunk * CHUNK + wave * 128;

  short8 ones;
#pragma unroll
  for (int j = 0; j < 8; j++) ones[j] = (short)0x3F80; // bf16 1.0

  f32x4 acc[4][4], aks[4];
#pragma unroll
  for (int i = 0; i < 4; i++) {
    aks[i] = zero4();
#pragma unroll
    for (int j = 0; j < 4; j++) acc[i][j] = zero4();
  }

  for (int it = 0; it < 4; it++) {
    const int s0 = s_w + it * 32 + quad * 8;
    short8 af[4], bfr[4];
#pragma unroll
    for (int mi = 0; mi < 4; mi++)
      af[mi] = *(const short8*)(vrow + (size_t)(mi * 16 + lrow) * 8192 + s0);
#pragma unroll
    for (int ni = 0; ni < 4; ni++)
      bfr[ni] = *(const short8*)(krow + (size_t)(ni * 16 + lrow) * 8192 + s0);
#pragma unroll
    for (int ni = 0; ni < 4; ni++) {
      aks[ni] = __builtin_amdgcn_mfma_f32_16x16x32_bf16(ones, bfr[ni], aks[ni], 0, 0, 0);
#pragma unroll
      for (int mi = 0; mi < 4; mi++)
        acc[mi][ni] = __builtin_amdgcn_mfma_f32_16x16x32_bf16(af[mi], bfr[ni], acc[mi][ni], 0, 0, 0);
    }
  }

  __syncthreads();
#pragma unroll
  for (int mi = 0; mi < 4; mi++)
#pragma unroll
    for (int ni = 0; ni < 4; ni++)
#pragma unroll
      for (int r = 0; r < 4; r++)
        atomicAdd(&ls_acc[(mi * 16 + quad * 4 + r) * 64 + ni * 16 + lrow], acc[mi][ni][r]);
  if (quad == 0) {
#pragma unroll
    for (int ni = 0; ni < 4; ni++) atomicAdd(&ls_ksum[ni * 16 + lrow], aks[ni][0]);
  }
  __syncthreads();

  float* op = kvt_part + ((size_t)chunk * 32 + bh) * 4096;
#pragma unroll
  for (int i = 0; i < 16; i++) op[tid + 256 * i] = ls_acc[tid + 256 * i];
  if (tid < 64) ksum_part[((size_t)chunk * 32 + bh) * 64 + tid] = ls_ksum[tid];
}

// ---------------------------------------------------------------------------
__global__ void kv_reduce_kernel(const float* __restrict__ kvt_part,
                                 const float* __restrict__ ksum_part,
                                 unsigned short* __restrict__ kvT,
                                 unsigned short* __restrict__ ksum_bf) {
  const int bh = blockIdx.x >> 2, seg = blockIdx.x & 3;
  const int idx = seg * 1024 + threadIdx.x * 4;
  float4 s = make_float4(0.f, 0.f, 0.f, 0.f);
#pragma unroll
  for (int c = 0; c < NSPLIT; c++) {
    float4 v = *(const float4*)&kvt_part[((size_t)c * 32 + bh) * 4096 + idx];
    s.x += v.x; s.y += v.y; s.z += v.z; s.w += v.w;
  }
  ushort4v o;
  o[0] = f2bf(s.x); o[1] = f2bf(s.y); o[2] = f2bf(s.z); o[3] = f2bf(s.w);
  *(ushort4v*)(kvT + (size_t)bh * 4096 + idx) = o;
  if (seg == 0 && threadIdx.x < 64) {
    float t = 0.f;
#pragma unroll
    for (int c = 0; c < NSPLIT; c++) t += ksum_part[((size_t)c * 32 + bh) * 64 + threadIdx.x];
    ksum_bf[bh * 64 + threadIdx.x] = f2bf(t);
  }
}

// ---------------------------------------------------------------------------
// numerator = phiQ @ KV, qk_sum = phiQ @ ksum (broadcast-column B => extra
// MFMA whose D rows line up lane-for-lane with the numerator rows).
__global__ __launch_bounds__(256) void attn_kernel(const unsigned short* __restrict__ phiQ,
                                                   const unsigned short* __restrict__ kvT,
                                                   const unsigned short* __restrict__ ksum_bf,
                                                   unsigned short* __restrict__ xattn) {
  const int bh = blockIdx.x & 31;
  const int st = blockIdx.x >> 5;
  const int b = bh >> 3, h = bh & 7;
  const int tid = threadIdx.x;
  const int wave = tid >> 6, lane = tid & 63;
  const int lrow = lane & 15, quad = lane >> 4;
  const size_t rowbase = (size_t)b * SEQ + st * 128 + wave * 32;

  f32x4 acc[2][4], aqs[2];
#pragma unroll
  for (int i = 0; i < 2; i++) {
    aqs[i] = zero4();
#pragma unroll
    for (int j = 0; j < 4; j++) acc[i][j] = zero4();
  }

#pragma unroll
  for (int kk = 0; kk < 64; kk += 32) {
    short8 ks = *(const short8*)(ksum_bf + bh * 64 + kk + quad * 8);
    short8 af[2];
#pragma unroll
    for (int mi = 0; mi < 2; mi++)
      af[mi] = *(const short8*)(phiQ + (rowbase + mi * 16 + lrow) * 512 + h * 64 + kk + quad * 8);
#pragma unroll
    for (int mi = 0; mi < 2; mi++)
      aqs[mi] = __builtin_amdgcn_mfma_f32_16x16x32_bf16(af[mi], ks, aqs[mi], 0, 0, 0);
#pragma unroll
    for (int ni = 0; ni < 4; ni++) {
      short8 bfr = *(const short8*)(kvT + (size_t)bh * 4096 + (ni * 16 + lrow) * 64 + kk + quad * 8);
#pragma unroll
      for (int mi = 0; mi < 2; mi++)
        acc[mi][ni] = __builtin_amdgcn_mfma_f32_16x16x32_bf16(af[mi], bfr, acc[mi][ni], 0, 0, 0);
    }
  }
#pragma unroll
  for (int mi = 0; mi < 2; mi++) {
#pragma unroll
    for (int r = 0; r < 4; r++) {
      float inv = 1.f / (aqs[mi][r] + 1e-6f);
      size_t m = rowbase + mi * 16 + quad * 4 + r;
#pragma unroll
      for (int ni = 0; ni < 4; ni++)
        xattn[m * 512 + h * 64 + ni * 16 + lrow] = f2bf(acc[mi][ni][r] * inv);
    }
  }
}

// ---------------------------------------------------------------------------
// out_gemm: 256x128 tile, 16 waves x (Wm=64 x Wn=32, single mat);
// acc = 32 AGPR -> 4 waves/SIMD. Same coarse dbuf + vmcnt(3).
__global__ __launch_bounds__(1024, 4) void out_gemm_kernel(const unsigned short* __restrict__ xattn,
                                                           const unsigned short* __restrict__ wo,
                                                           const float* __restrict__ ob,
                                                           float* __restrict__ out) {
  const int wg = (blockIdx.x & 7) * 64 + (blockIdx.x >> 3); // T1 swizzle
  const int mt = wg >> 2, nt = wg & 3;
  const int m0 = mt * 256, n0 = nt * 128;
  const int tid = threadIdx.x;
  const int wave = tid >> 6, lane = tid & 63;
  const int lrow = lane & 15, quad = lane >> 4;
  const int m_off = (wave >> 2) * 64;
  const int n_off = (wave & 3) * 32;

  // Per buffer (shorts): sA[0..16384) 256x64, sB[16384..24576) 128x64.
  __shared__ unsigned short lds[2 * 24576]; // 96 KB

  const int srow_l = lane >> 3;
  const int kq_l = (lane & 7) ^ srow_l;
  const int swz = lrow & 7;

  f32x4 acc[4][2];
#pragma unroll
  for (int i = 0; i < 4; i++)
#pragma unroll
    for (int j = 0; j < 2; j++) acc[i][j] = zero4();

  // 3 stage issues per wave: 2 for A, 1 for B
  auto stage = [&](unsigned short* dst, int k0) {
#pragma unroll
    for (int i = 0; i < 2; i++) {
      int ig = wave * 2 + i;
      gload_lds16(xattn + (size_t)(m0 + ig * 8 + srow_l) * 512 + k0 + kq_l * 8,
                  dst + ig * 512);
    }
    gload_lds16(wo + (size_t)(n0 + wave * 8 + srow_l) * 512 + k0 + kq_l * 8,
                dst + 16384 + wave * 512);
  };

  stage(lds, 0);

  for (int t = 0; t < 8; ++t) {
    unsigned short* cur = lds + (t & 1) * 24576;
    if (t < 7) {
      stage(lds + ((t + 1) & 1) * 24576, (t + 1) * 64);
      asm volatile("s_waitcnt vmcnt(3)" ::: "memory");
    } else {
      asm volatile("s_waitcnt vmcnt(0)" ::: "memory");
    }
    __builtin_amdgcn_s_barrier();

#pragma unroll
    for (int kk = 0; kk < 64; kk += 32) {
      const int e8 = (kk >> 3) + quad;
      short8 af[4], bfr[2];
#pragma unroll
      for (int mi = 0; mi < 4; mi++)
        af[mi] = *(const short8*)(cur + (m_off + mi * 16 + lrow) * 64 + ((e8 ^ swz) << 3));
#pragma unroll
      for (int ni = 0; ni < 2; ni++)
        bfr[ni] = *(const short8*)(cur + 16384 + (n_off + ni * 16 + lrow) * 64 + ((e8 ^ swz) << 3));
#pragma unroll
      for (int ni = 0; ni < 2; ni++)
#pragma unroll
        for (int mi = 0; mi < 4; mi++)
          acc[mi][ni] = __builtin_amdgcn_mfma_f32_16x16x32_bf16(af[mi], bfr[ni], acc[mi][ni], 0, 0, 0);
    }
    __builtin_amdgcn_s_barrier();
  }

#pragma unroll
  for (int ni = 0; ni < 2; ni++) {
    int n = n0 + n_off + ni * 16 + lrow;
    float bb = ob[n];
#pragma unroll
    for (int mi = 0; mi < 4; mi++)
#pragma unroll
      for (int r = 0; r < 4; r++) {
        int m = m0 + m_off + mi * 16 + quad * 4 + r;
        out[(size_t)m * 512 + n] = acc[mi][ni][r] + bb;
      }
  }
}

// ---------------------------------------------------------------------------
extern "C" void kernel_launch(void* const* d_in, const int* in_sizes, int n_in,
                              void* d_out, int out_size, void* d_ws, size_t ws_size,
                              hipStream_t stream) {
  char* ws = (char*)d_ws;
  size_t off = 0;
  auto alloc = [&](size_t bytes) -> void* {
    void* p = ws + off;
    off += (bytes + 255) & ~(size_t)255;
    return p;
  };
  unsigned short* wbf = (unsigned short*)alloc((size_t)7 * 262144 * 2);     // 3.67 MB
  unsigned short* phiQ = (unsigned short*)alloc((size_t)BSROWS * 512 * 2);  // 33.5 MB
  unsigned short* kT = (unsigned short*)alloc((size_t)BSROWS * 512 * 2);    // 33.5 MB  [bh][d][s]
  unsigned short* vT = (unsigned short*)alloc((size_t)BSROWS * 512 * 2);    // 33.5 MB  [bh][e][s]
  unsigned short* xbf = (unsigned short*)alloc((size_t)3 * BSROWS * 512 * 2); // 100.7 MB
  if (off > ws_size) return; // insufficient workspace; fail visibly

  // xbf region reused after proj_kernel: x_attn + kv partials
  char* xr = (char*)xbf;
  unsigned short* xattn = (unsigned short*)xr;              // 67,108,864 B
  float* kvt_part = (float*)(xr + 67108864);                //  8,388,608 B
  float* ksum_part = (float*)(xr + 75497472);               //    131,072 B
  unsigned short* kvT = (unsigned short*)(xr + 75628544);   //    262,144 B
  unsigned short* ksum_bf = (unsigned short*)(xr + 75890688);

  WPtrs wp;
  for (int i = 0; i < 7; i++) wp.w[i] = (const float*)d_in[3 + i];
  convert_weights_kernel<<<1792, 256, 0, stream>>>(wp, wbf);
  convert_x_kernel<<<24576, 256, 0, stream>>>((const float*)d_in[0], (const float*)d_in[1],
                                              (const float*)d_in[2], xbf);

  ProjArgs pa;
  pa.b1[0] = (const float*)d_in[10]; pa.b2[0] = (const float*)d_in[11];
  pa.b1[1] = (const float*)d_in[12]; pa.b2[1] = (const float*)d_in[13];
  pa.b1[2] = (const float*)d_in[14]; pa.b2[2] = (const float*)d_in[15];
  pa.out[0] = phiQ; pa.out[1] = kT; pa.out[2] = vT;
  proj_kernel<<<dim3(512, 3), 1024, 0, stream>>>(pa, wbf, xbf);

  kv_kernel<<<512, 256, 0, stream>>>(kT, vT, kvt_part, ksum_part);
  kv_reduce_kernel<<<128, 256, 0, stream>>>(kvt_part, ksum_part, kvT, ksum_bf);
  attn_kernel<<<2048, 256, 0, stream>>>(phiQ, kvT, ksum_bf, xattn);
  out_gemm_kernel<<<512, 1024, 0, stream>>>(xattn, wbf + (size_t)6 * 262144,
                                            (const float*)d_in[16], (float*)d_out);
}

// Round 4
// 460.622 us; speedup vs baseline: 1.0557x; 1.0358x over previous
//
#include <hip/hip_runtime.h>
#include <stdint.h>

// ---------------------------------------------------------------------------
// MultiHeadLinearAttention (B=4,S=8192,D=512,H=8,dk=64), fp32 in/out.
// Round 7: FUSE convert_x into proj. Rounds 0-3 proved proj's ~155-160us is
// schedule-insensitive (serial 8-wave = coarse-dbuf = 16-wave TLP@42%occ;
// 4-phase pinning regressed). So stop rescheduling proj; delete the 288MB
// convert_x pass instead: proj A-operand is now reg-staged straight from
// fp32 q/k/v (coalesced float4 loads -> f2bf -> swizzled ds_write_b64),
// W1/W2 still via global_load_lds. proj absorbs the conversion in its slack
// (HBM 14%, LDS ~50%); the standalone pass could not be absorbed anywhere.
//   - T1 XCD swizzle KEPT (r2: proj FETCH 203->74 MB).
//   - 16-wave/256x128/dual-acc structure KEPT from r3 (equal-best, 42% occ).
//   - No counted vmcnt games: nothing in flight across barriers; explicit
//     vmcnt(0)+lgkmcnt(0) before end barrier (gload_lds has no dest reg, the
//     compiler cannot auto-wait on it; ds_write needs lgkm drain pre-barrier).
// XOR swizzle (verified: 0 bank conflicts): logical (row, octet e8) stored at
// row*64 + ((e8^(row&7))*8) shorts; ds_write_b64 half-octets at +half*4.
// MFMA 16x16x32_bf16 layouts (verified m89/m91):
//   A: m=lane&15, k=quad*8+j ; B: n=lane&15, k=quad*8+j
//   D: col=lane&15, row=quad*4+r
// ---------------------------------------------------------------------------

#define DMODEL 512
#define NHEAD 8
#define BATCH 4
#define SEQ 8192
#define BSROWS (BATCH * SEQ) // 32768
#define NSPLIT 16
#define CHUNK (SEQ / NSPLIT) // 512

typedef __attribute__((ext_vector_type(8))) short short8;
typedef __attribute__((ext_vector_type(4))) short short4v;
typedef __attribute__((ext_vector_type(4))) float f32x4;
typedef __attribute__((ext_vector_type(4))) unsigned short ushort4v;

__device__ __forceinline__ unsigned short f2bf(float f) {
  union { float f; uint32_t u; } v; v.f = f;
  uint32_t u = v.u;
  u += 0x7fffu + ((u >> 16) & 1u); // RNE
  return (unsigned short)(u >> 16);
}
__device__ __forceinline__ float bf2f(unsigned short h) {
  union { float f; uint32_t u; } v; v.u = ((uint32_t)h) << 16; return v.f;
}
__device__ __forceinline__ f32x4 zero4() {
  f32x4 z; z[0] = 0.f; z[1] = 0.f; z[2] = 0.f; z[3] = 0.f; return z;
}
__device__ __forceinline__ void gload_lds16(const unsigned short* g, unsigned short* l) {
  __builtin_amdgcn_global_load_lds((const __attribute__((address_space(1))) void*)g,
                                   (__attribute__((address_space(3))) void*)l, 16, 0, 0);
}

// ---------------------------------------------------------------------------
struct WPtrs { const float* w[7]; };

__global__ void convert_weights_kernel(WPtrs wp, unsigned short* __restrict__ wbf) {
  int gid = blockIdx.x * 256 + threadIdx.x;  // 458752 total
  int which = gid >> 16;                     // 65536 float4 per matrix
  int rem = gid & 65535;
  float4 v = ((const float4*)wp.w[which])[rem];
  ushort4v o;
  o[0] = f2bf(v.x); o[1] = f2bf(v.y); o[2] = f2bf(v.z); o[3] = f2bf(v.w);
  *(ushort4v*)(wbf + (size_t)which * 262144 + (size_t)rem * 4) = o;
}

// ---------------------------------------------------------------------------
// Gated projection: 256x128 tile, 16 waves x (Wm=64 x Wn=32, dual-mat).
// A reg-staged from fp32 (fused convert), W1/W2 via global_load_lds.
struct ProjArgs {
  const float* xf[3];
  const float* b1[3];
  const float* b2[3];
  unsigned short* out[3]; // which0: phiQ [m][512]; which1/2: [bh][d][8192]
};

__global__ __launch_bounds__(1024, 4) void proj_kernel(ProjArgs pa,
                                                       const unsigned short* __restrict__ wbf) {
  const int which = blockIdx.y;
  const float* __restrict__ xf = pa.xf[which];
  const unsigned short* __restrict__ w1 = wbf + (size_t)which * 524288;
  const unsigned short* __restrict__ w2 = w1 + 262144;
  const float* __restrict__ b1p = pa.b1[which];
  const float* __restrict__ b2p = pa.b2[which];
  unsigned short* __restrict__ outp = pa.out[which];
  const bool PHI = (which < 2);

  // T1: XCD-aware bijective swizzle; 512 blocks/slice, 512%8==0.
  const int wg = (blockIdx.x & 7) * 64 + (blockIdx.x >> 3);
  const int mt = wg >> 2, nt = wg & 3;
  const int m0 = mt * 256, n0 = nt * 128;
  const int tid = threadIdx.x;
  const int wave = tid >> 6, lane = tid & 63;   // wave 0..15
  const int lrow = lane & 15, quad = lane >> 4;
  const int m_off = (wave >> 2) * 64;           // 4 m-positions
  const int n_off = (wave & 3) * 32;            // 4 n-positions

  // Per buffer (shorts): sA[0..16384) 256x64, sB1[16384..24576) 128x64,
  // sB2[24576..32768) 128x64.  Double-buffered -> 65536 shorts = 128 KB.
  __shared__ unsigned short lds[2 * 32768];

  const int srow_l = lane >> 3;            // 0..7 within 8-row issue (W path)
  const int kq_l = (lane & 7) ^ srow_l;    // swizzled source octet (W path)
  const int swz = lrow & 7;

  // A reg-stage mapping: inst j covers rows [j*64 + wave*4, +4), 16 lanes/row
  // cover the row's 64 k-floats contiguously (fully coalesced float4 loads).
  const int arow_l = wave * 4 + (lane >> 4); // + j*64
  const int ac = lane & 15;                  // float4 index within row
  const int ao8 = ac >> 1, ahalf = ac & 1;   // octet / half-octet for ds_write

  f32x4 acc1[4][2], acc2[4][2];
#pragma unroll
  for (int i = 0; i < 4; i++)
#pragma unroll
    for (int j = 0; j < 2; j++) { acc1[i][j] = zero4(); acc2[i][j] = zero4(); }

  float4 a4[4];
  auto stageA_load = [&](int k0) {
#pragma unroll
    for (int j = 0; j < 4; j++) {
      int row = j * 64 + arow_l;
      a4[j] = *(const float4*)(xf + (size_t)(m0 + row) * 512 + k0 + ac * 4);
    }
  };
  auto stageA_write = [&](unsigned short* dstA) {
#pragma unroll
    for (int j = 0; j < 4; j++) {
      int row = j * 64 + arow_l;
      short4v o;
      o[0] = (short)f2bf(a4[j].x); o[1] = (short)f2bf(a4[j].y);
      o[2] = (short)f2bf(a4[j].z); o[3] = (short)f2bf(a4[j].w);
      *(short4v*)(dstA + row * 64 + ((ao8 ^ (row & 7)) << 3) + ahalf * 4) = o;
    }
  };
  auto stageW = [&](unsigned short* dst, int k0) {
    size_t roff = (size_t)(n0 + wave * 8 + srow_l) * 512 + k0 + kq_l * 8;
    gload_lds16(w1 + roff, dst + 16384 + wave * 512);
    gload_lds16(w2 + roff, dst + 24576 + wave * 512);
  };

  // ---- prologue: stage tile 0 into buffer 0 ----
  stageA_load(0);
  stageW(lds, 0);
  stageA_write(lds);  // compiler auto-waits vmcnt for a4 before the cvt
  asm volatile("s_waitcnt vmcnt(0) lgkmcnt(0)" ::: "memory");
  __builtin_amdgcn_s_barrier();

  for (int t = 0; t < 8; ++t) {
    unsigned short* cur = lds + (t & 1) * 32768;
    unsigned short* nxt = lds + ((t + 1) & 1) * 32768;
    if (t < 7) {
      stageA_load((t + 1) * 64);  // fp32 A -> regs (latency hides under MFMA)
      stageW(nxt, (t + 1) * 64);  // W -> LDS direct
    }

#pragma unroll
    for (int kk = 0; kk < 64; kk += 32) {
      const int e8 = (kk >> 3) + quad;
      short8 af[4], b1f[2], b2f[2];
#pragma unroll
      for (int mi = 0; mi < 4; mi++)
        af[mi] = *(const short8*)(cur + (m_off + mi * 16 + lrow) * 64 + ((e8 ^ swz) << 3));
#pragma unroll
      for (int ni = 0; ni < 2; ni++) {
        int rr = n_off + ni * 16 + lrow;
        b1f[ni] = *(const short8*)(cur + 16384 + rr * 64 + ((e8 ^ swz) << 3));
        b2f[ni] = *(const short8*)(cur + 24576 + rr * 64 + ((e8 ^ swz) << 3));
      }
#pragma unroll
      for (int ni = 0; ni < 2; ni++)
#pragma unroll
        for (int mi = 0; mi < 4; mi++) {
          acc1[mi][ni] = __builtin_amdgcn_mfma_f32_16x16x32_bf16(af[mi], b1f[ni], acc1[mi][ni], 0, 0, 0);
          acc2[mi][ni] = __builtin_amdgcn_mfma_f32_16x16x32_bf16(af[mi], b2f[ni], acc2[mi][ni], 0, 0, 0);
        }
    }

    if (t < 7) stageA_write(nxt);  // cvt + swizzled ds_write into nxt buffer
    // vmcnt(0): W gload_lds (no dest reg -> compiler can't auto-wait) landed;
    // lgkmcnt(0): our ds_writes committed. Both issued ~a full K-tile ago.
    asm volatile("s_waitcnt vmcnt(0) lgkmcnt(0)" ::: "memory");
    __builtin_amdgcn_s_barrier();
  }

  if (which == 0) {
#pragma unroll
    for (int ni = 0; ni < 2; ni++) {
      int n = n0 + n_off + ni * 16 + lrow;
      float bb1 = b1p[n], bb2 = b2p[n];
#pragma unroll
      for (int mi = 0; mi < 4; mi++)
#pragma unroll
        for (int r = 0; r < 4; r++) {
          int m = m0 + m_off + mi * 16 + quad * 4 + r;
          float v1 = acc1[mi][ni][r] + bb1;
          float v2 = acc2[mi][ni][r] + bb2;
          float y = v1 * (1.f / (1.f + __expf(-v1))) * v2; // silu(v1)*v2
          y = (y > 0.f) ? (y + 1.f) : __expf(y);           // elu(y)+1
          outp[(size_t)m * 512 + n] = f2bf(y);
        }
    }
  } else {
    // transposed store: [bh][d][s], 8B (4 consecutive s) per lane per (mi,ni)
    const int bI = m0 >> 13;
    const int sb = (m0 & 8191) + m_off + quad * 4;
#pragma unroll
    for (int ni = 0; ni < 2; ni++) {
      int n = n0 + n_off + ni * 16 + lrow;
      float bb1 = b1p[n], bb2 = b2p[n];
      int h = n >> 6, d = n & 63;
      unsigned short* dst0 = outp + (((size_t)bI * 8 + h) * 64 + d) * 8192 + sb;
#pragma unroll
      for (int mi = 0; mi < 4; mi++) {
        short4v o;
#pragma unroll
        for (int r = 0; r < 4; r++) {
          float v1 = acc1[mi][ni][r] + bb1;
          float v2 = acc2[mi][ni][r] + bb2;
          float y = v1 * (1.f / (1.f + __expf(-v1))) * v2;
          if (PHI) y = (y > 0.f) ? (y + 1.f) : __expf(y);
          o[r] = (short)f2bf(y);
        }
        *(short4v*)(dst0 + mi * 16) = o;
      }
    }
  }
}

// ---------------------------------------------------------------------------
// KV^T partials from transposed inputs: D[e][d] = sum_s vT[e][s]*kT[d][s].
__global__ __launch_bounds__(256) void kv_kernel(const unsigned short* __restrict__ kT,
                                                 const unsigned short* __restrict__ vT,
                                                 float* __restrict__ kvt_part,
                                                 float* __restrict__ ksum_part) {
  const int chunk = blockIdx.x & (NSPLIT - 1);
  const int bh = blockIdx.x >> 4;
  const int tid = threadIdx.x;
  const int wave = tid >> 6, lane = tid & 63;
  const int lrow = lane & 15, quad = lane >> 4;

  __shared__ float ls_acc[4096];
  __shared__ float ls_ksum[64];
  if (tid < 64) ls_ksum[tid] = 0.f;
#pragma unroll
  for (int i = 0; i < 16; i++) ls_acc[tid + 256 * i] = 0.f;

  const unsigned short* vrow = vT + (size_t)bh * 64 * 8192;
  const unsigned short* krow = kT + (size_t)bh * 64 * 8192;
  const int s_w = chunk * CHUNK + wave * 128;

  short8 ones;
#pragma unroll
  for (int j = 0; j < 8; j++) ones[j] = (short)0x3F80; // bf16 1.0

  f32x4 acc[4][4], aks[4];
#pragma unroll
  for (int i = 0; i < 4; i++) {
    aks[i] = zero4();
#pragma unroll
    for (int j = 0; j < 4; j++) acc[i][j] = zero4();
  }

  for (int it = 0; it < 4; it++) {
    const int s0 = s_w + it * 32 + quad * 8;
    short8 af[4], bfr[4];
#pragma unroll
    for (int mi = 0; mi < 4; mi++)
      af[mi] = *(const short8*)(vrow + (size_t)(mi * 16 + lrow) * 8192 + s0);
#pragma unroll
    for (int ni = 0; ni < 4; ni++)
      bfr[ni] = *(const short8*)(krow + (size_t)(ni * 16 + lrow) * 8192 + s0);
#pragma unroll
    for (int ni = 0; ni < 4; ni++) {
      aks[ni] = __builtin_amdgcn_mfma_f32_16x16x32_bf16(ones, bfr[ni], aks[ni], 0, 0, 0);
#pragma unroll
      for (int mi = 0; mi < 4; mi++)
        acc[mi][ni] = __builtin_amdgcn_mfma_f32_16x16x32_bf16(af[mi], bfr[ni], acc[mi][ni], 0, 0, 0);
    }
  }

  __syncthreads();
#pragma unroll
  for (int mi = 0; mi < 4; mi++)
#pragma unroll
    for (int ni = 0; ni < 4; ni++)
#pragma unroll
      for (int r = 0; r < 4; r++)
        atomicAdd(&ls_acc[(mi * 16 + quad * 4 + r) * 64 + ni * 16 + lrow], acc[mi][ni][r]);
  if (quad == 0) {
#pragma unroll
    for (int ni = 0; ni < 4; ni++) atomicAdd(&ls_ksum[ni * 16 + lrow], aks[ni][0]);
  }
  __syncthreads();

  float* op = kvt_part + ((size_t)chunk * 32 + bh) * 4096;
#pragma unroll
  for (int i = 0; i < 16; i++) op[tid + 256 * i] = ls_acc[tid + 256 * i];
  if (tid < 64) ksum_part[((size_t)chunk * 32 + bh) * 64 + tid] = ls_ksum[tid];
}

// ---------------------------------------------------------------------------
__global__ void kv_reduce_kernel(const float* __restrict__ kvt_part,
                                 const float* __restrict__ ksum_part,
                                 unsigned short* __restrict__ kvT,
                                 unsigned short* __restrict__ ksum_bf) {
  const int bh = blockIdx.x >> 2, seg = blockIdx.x & 3;
  const int idx = seg * 1024 + threadIdx.x * 4;
  float4 s = make_float4(0.f, 0.f, 0.f, 0.f);
#pragma unroll
  for (int c = 0; c < NSPLIT; c++) {
    float4 v = *(const float4*)&kvt_part[((size_t)c * 32 + bh) * 4096 + idx];
    s.x += v.x; s.y += v.y; s.z += v.z; s.w += v.w;
  }
  ushort4v o;
  o[0] = f2bf(s.x); o[1] = f2bf(s.y); o[2] = f2bf(s.z); o[3] = f2bf(s.w);
  *(ushort4v*)(kvT + (size_t)bh * 4096 + idx) = o;
  if (seg == 0 && threadIdx.x < 64) {
    float t = 0.f;
#pragma unroll
    for (int c = 0; c < NSPLIT; c++) t += ksum_part[((size_t)c * 32 + bh) * 64 + threadIdx.x];
    ksum_bf[bh * 64 + threadIdx.x] = f2bf(t);
  }
}

// ---------------------------------------------------------------------------
// numerator = phiQ @ KV, qk_sum = phiQ @ ksum (broadcast-column B => extra
// MFMA whose D rows line up lane-for-lane with the numerator rows).
__global__ __launch_bounds__(256) void attn_kernel(const unsigned short* __restrict__ phiQ,
                                                   const unsigned short* __restrict__ kvT,
                                                   const unsigned short* __restrict__ ksum_bf,
                                                   unsigned short* __restrict__ xattn) {
  const int bh = blockIdx.x & 31;
  const int st = blockIdx.x >> 5;
  const int b = bh >> 3, h = bh & 7;
  const int tid = threadIdx.x;
  const int wave = tid >> 6, lane = tid & 63;
  const int lrow = lane & 15, quad = lane >> 4;
  const size_t rowbase = (size_t)b * SEQ + st * 128 + wave * 32;

  f32x4 acc[2][4], aqs[2];
#pragma unroll
  for (int i = 0; i < 2; i++) {
    aqs[i] = zero4();
#pragma unroll
    for (int j = 0; j < 4; j++) acc[i][j] = zero4();
  }

#pragma unroll
  for (int kk = 0; kk < 64; kk += 32) {
    short8 ks = *(const short8*)(ksum_bf + bh * 64 + kk + quad * 8);
    short8 af[2];
#pragma unroll
    for (int mi = 0; mi < 2; mi++)
      af[mi] = *(const short8*)(phiQ + (rowbase + mi * 16 + lrow) * 512 + h * 64 + kk + quad * 8);
#pragma unroll
    for (int mi = 0; mi < 2; mi++)
      aqs[mi] = __builtin_amdgcn_mfma_f32_16x16x32_bf16(af[mi], ks, aqs[mi], 0, 0, 0);
#pragma unroll
    for (int ni = 0; ni < 4; ni++) {
      short8 bfr = *(const short8*)(kvT + (size_t)bh * 4096 + (ni * 16 + lrow) * 64 + kk + quad * 8);
#pragma unroll
      for (int mi = 0; mi < 2; mi++)
        acc[mi][ni] = __builtin_amdgcn_mfma_f32_16x16x32_bf16(af[mi], bfr, acc[mi][ni], 0, 0, 0);
    }
  }
#pragma unroll
  for (int mi = 0; mi < 2; mi++) {
#pragma unroll
    for (int r = 0; r < 4; r++) {
      float inv = 1.f / (aqs[mi][r] + 1e-6f);
      size_t m = rowbase + mi * 16 + quad * 4 + r;
#pragma unroll
      for (int ni = 0; ni < 4; ni++)
        xattn[m * 512 + h * 64 + ni * 16 + lrow] = f2bf(acc[mi][ni][r] * inv);
    }
  }
}

// ---------------------------------------------------------------------------
// out_gemm: 256x128 tile, 16 waves x (Wm=64 x Wn=32, single mat);
// acc = 32 AGPR -> 4 waves/SIMD. Coarse dbuf + vmcnt(3). (unchanged from r3)
__global__ __launch_bounds__(1024, 4) void out_gemm_kernel(const unsigned short* __restrict__ xattn,
                                                           const unsigned short* __restrict__ wo,
                                                           const float* __restrict__ ob,
                                                           float* __restrict__ out) {
  const int wg = (blockIdx.x & 7) * 64 + (blockIdx.x >> 3); // T1 swizzle
  const int mt = wg >> 2, nt = wg & 3;
  const int m0 = mt * 256, n0 = nt * 128;
  const int tid = threadIdx.x;
  const int wave = tid >> 6, lane = tid & 63;
  const int lrow = lane & 15, quad = lane >> 4;
  const int m_off = (wave >> 2) * 64;
  const int n_off = (wave & 3) * 32;

  // Per buffer (shorts): sA[0..16384) 256x64, sB[16384..24576) 128x64.
  __shared__ unsigned short lds[2 * 24576]; // 96 KB

  const int srow_l = lane >> 3;
  const int kq_l = (lane & 7) ^ srow_l;
  const int swz = lrow & 7;

  f32x4 acc[4][2];
#pragma unroll
  for (int i = 0; i < 4; i++)
#pragma unroll
    for (int j = 0; j < 2; j++) acc[i][j] = zero4();

  // 3 stage issues per wave: 2 for A, 1 for B
  auto stage = [&](unsigned short* dst, int k0) {
#pragma unroll
    for (int i = 0; i < 2; i++) {
      int ig = wave * 2 + i;
      gload_lds16(xattn + (size_t)(m0 + ig * 8 + srow_l) * 512 + k0 + kq_l * 8,
                  dst + ig * 512);
    }
    gload_lds16(wo + (size_t)(n0 + wave * 8 + srow_l) * 512 + k0 + kq_l * 8,
                dst + 16384 + wave * 512);
  };

  stage(lds, 0);

  for (int t = 0; t < 8; ++t) {
    unsigned short* cur = lds + (t & 1) * 24576;
    if (t < 7) {
      stage(lds + ((t + 1) & 1) * 24576, (t + 1) * 64);
      asm volatile("s_waitcnt vmcnt(3)" ::: "memory");
    } else {
      asm volatile("s_waitcnt vmcnt(0)" ::: "memory");
    }
    __builtin_amdgcn_s_barrier();

#pragma unroll
    for (int kk = 0; kk < 64; kk += 32) {
      const int e8 = (kk >> 3) + quad;
      short8 af[4], bfr[2];
#pragma unroll
      for (int mi = 0; mi < 4; mi++)
        af[mi] = *(const short8*)(cur + (m_off + mi * 16 + lrow) * 64 + ((e8 ^ swz) << 3));
#pragma unroll
      for (int ni = 0; ni < 2; ni++)
        bfr[ni] = *(const short8*)(cur + 16384 + (n_off + ni * 16 + lrow) * 64 + ((e8 ^ swz) << 3));
#pragma unroll
      for (int ni = 0; ni < 2; ni++)
#pragma unroll
        for (int mi = 0; mi < 4; mi++)
          acc[mi][ni] = __builtin_amdgcn_mfma_f32_16x16x32_bf16(af[mi], bfr[ni], acc[mi][ni], 0, 0, 0);
    }
    __builtin_amdgcn_s_barrier();
  }

#pragma unroll
  for (int ni = 0; ni < 2; ni++) {
    int n = n0 + n_off + ni * 16 + lrow;
    float bb = ob[n];
#pragma unroll
    for (int mi = 0; mi < 4; mi++)
#pragma unroll
      for (int r = 0; r < 4; r++) {
        int m = m0 + m_off + mi * 16 + quad * 4 + r;
        out[(size_t)m * 512 + n] = acc[mi][ni][r] + bb;
      }
  }
}

// ---------------------------------------------------------------------------
extern "C" void kernel_launch(void* const* d_in, const int* in_sizes, int n_in,
                              void* d_out, int out_size, void* d_ws, size_t ws_size,
                              hipStream_t stream) {
  char* ws = (char*)d_ws;
  size_t off = 0;
  auto alloc = [&](size_t bytes) -> void* {
    void* p = ws + off;
    off += (bytes + 255) & ~(size_t)255;
    return p;
  };
  unsigned short* wbf = (unsigned short*)alloc((size_t)7 * 262144 * 2);     // 3.67 MB
  unsigned short* phiQ = (unsigned short*)alloc((size_t)BSROWS * 512 * 2);  // 33.5 MB
  unsigned short* kT = (unsigned short*)alloc((size_t)BSROWS * 512 * 2);    // 33.5 MB  [bh][d][s]
  unsigned short* vT = (unsigned short*)alloc((size_t)BSROWS * 512 * 2);    // 33.5 MB  [bh][e][s]
  char* xr = (char*)alloc((size_t)3 * BSROWS * 512 * 2);                    // scratch region
  if (off > ws_size) return; // insufficient workspace; fail visibly

  // scratch region: x_attn + kv partials
  unsigned short* xattn = (unsigned short*)xr;              // 67,108,864 B
  float* kvt_part = (float*)(xr + 67108864);                //  8,388,608 B
  float* ksum_part = (float*)(xr + 75497472);               //    131,072 B
  unsigned short* kvT = (unsigned short*)(xr + 75628544);   //    262,144 B
  unsigned short* ksum_bf = (unsigned short*)(xr + 75890688);

  WPtrs wp;
  for (int i = 0; i < 7; i++) wp.w[i] = (const float*)d_in[3 + i];
  convert_weights_kernel<<<1792, 256, 0, stream>>>(wp, wbf);

  ProjArgs pa;
  pa.xf[0] = (const float*)d_in[0]; pa.xf[1] = (const float*)d_in[1];
  pa.xf[2] = (const float*)d_in[2];
  pa.b1[0] = (const float*)d_in[10]; pa.b2[0] = (const float*)d_in[11];
  pa.b1[1] = (const float*)d_in[12]; pa.b2[1] = (const float*)d_in[13];
  pa.b1[2] = (const float*)d_in[14]; pa.b2[2] = (const float*)d_in[15];
  pa.out[0] = phiQ; pa.out[1] = kT; pa.out[2] = vT;
  proj_kernel<<<dim3(512, 3), 1024, 0, stream>>>(pa, wbf);

  kv_kernel<<<512, 256, 0, stream>>>(kT, vT, kvt_part, ksum_part);
  kv_reduce_kernel<<<128, 256, 0, stream>>>(kvt_part, ksum_part, kvT, ksum_bf);
  attn_kernel<<<2048, 256, 0, stream>>>(phiQ, kvT, ksum_bf, xattn);
  out_gemm_kernel<<<512, 1024, 0, stream>>>(xattn, wbf + (size_t)6 * 262144,
                                            (const float*)d_in[16], (float*)d_out);
}